// Round 1
// 9815.076 us; speedup vs baseline: 1.3252x; 1.3252x over previous
//
#include <hip/hip_runtime.h>
#include <math.h>

#define B_   64
#define T_   256
#define D_   512
#define H_   1024
#define G3_  3072
#define O_   64
#define NTOK (B_*T_)     // 16384
#define TC_  64          // timesteps per chunk
#define NCH_ 4           // chunks

// ---------------------------------------------------------------------------
// init: zero h slot 0 (fp64) and flags. grid 256 x 256.
// ---------------------------------------------------------------------------
__global__ __launch_bounds__(256) void init_ws(double* __restrict__ hs,
                                               int* __restrict__ flags)
{
  int idx = blockIdx.x*256 + threadIdx.x;   // 0..65535
  hs[idx] = 0.0;                            // slot 0 = [64][1024] doubles
  if (idx < 4096) flags[idx] = 0;
}

// ---------------------------------------------------------------------------
// Stage A (per chunk): gx[(tl*64+b)][g] = emb[x[b,t_base+tl]] . W_ih[g] + b_ih
// R3-proven 64x64 tile structure; fp32 LDS tiles (exact), fp64 FMA accum.
// Block = 64 timesteps of one batch x 64 gates. grid = 64*48 = 3072.
// ---------------------------------------------------------------------------
__global__ __launch_bounds__(256) void stage_a(
    const int* __restrict__ x, const float* __restrict__ emb,
    const float* __restrict__ W_ih, const float* __restrict__ b_ih,
    double* __restrict__ gx, int t_base)
{
  __shared__ float As[64][33];
  __shared__ float Bs[64][33];
  const int tid = threadIdx.x;
  const int b = blockIdx.x & 63, nBlk = blockIdx.x >> 6;
  const int g0 = nBlk*64;

  const int r = tid >> 2, c8 = tid & 3;     // r = t_local row / gate row
  const float* ap = emb  + (size_t)x[b*T_ + t_base + r]*D_ + c8*8;
  const float* bp = W_ih + (size_t)(g0 + r)*D_ + c8*8;
  const int tx = tid & 15, ty = tid >> 4;

  double acc[4][4];
  #pragma unroll
  for (int i = 0; i < 4; ++i)
    #pragma unroll
    for (int j = 0; j < 4; ++j) acc[i][j] = 0.0;

  float4 a0 = *(const float4*)(ap), a1 = *(const float4*)(ap + 4);
  float4 b0 = *(const float4*)(bp), b1 = *(const float4*)(bp + 4);

  for (int kb = 0; kb < 16; ++kb){
    __syncthreads();
    As[r][c8*8+0]=a0.x; As[r][c8*8+1]=a0.y; As[r][c8*8+2]=a0.z; As[r][c8*8+3]=a0.w;
    As[r][c8*8+4]=a1.x; As[r][c8*8+5]=a1.y; As[r][c8*8+6]=a1.z; As[r][c8*8+7]=a1.w;
    Bs[r][c8*8+0]=b0.x; Bs[r][c8*8+1]=b0.y; Bs[r][c8*8+2]=b0.z; Bs[r][c8*8+3]=b0.w;
    Bs[r][c8*8+4]=b1.x; Bs[r][c8*8+5]=b1.y; Bs[r][c8*8+6]=b1.z; Bs[r][c8*8+7]=b1.w;
    __syncthreads();
    if (kb < 15){
      a0 = *(const float4*)(ap + (kb+1)*32);  a1 = *(const float4*)(ap + (kb+1)*32 + 4);
      b0 = *(const float4*)(bp + (kb+1)*32);  b1 = *(const float4*)(bp + (kb+1)*32 + 4);
    }
    #pragma unroll
    for (int k = 0; k < 32; ++k){
      double av[4], bv[4];
      #pragma unroll
      for (int i = 0; i < 4; ++i) av[i] = (double)As[ty*4+i][k];
      #pragma unroll
      for (int j = 0; j < 4; ++j) bv[j] = (double)Bs[tx*4+j][k];
      #pragma unroll
      for (int i = 0; i < 4; ++i)
        #pragma unroll
        for (int j = 0; j < 4; ++j) acc[i][j] = fma(av[i], bv[j], acc[i][j]);
    }
  }

  double bi[4];
  #pragma unroll
  for (int j = 0; j < 4; ++j) bi[j] = (double)b_ih[g0 + tx*4 + j];
  #pragma unroll
  for (int i = 0; i < 4; ++i){
    int tl = ty*4 + i;
    size_t rowoff = ((size_t)tl*B_ + b)*G3_ + g0 + tx*4;
    #pragma unroll
    for (int j = 0; j < 4; ++j)
      gx[rowoff + j] = acc[i][j] + bi[j];
  }
}

// ---------------------------------------------------------------------------
// GRU recurrence (per chunk), fp64. Persistent: 256 WGs (1/CU), WG wg owns
// h cols wg*4..+3; its 12 W_hh gate-rows live in LDS as fp64.
//
// R4 coherence scheme (fence-free):
//  - h(t+1) stores are RELAXED agent-scope atomics -> sc0 sc1, write-through
//    to LLC (coherence point). No release fence (no buffer_wbl2).
//  - h(t) loads are NORMAL cached loads. Safe because hs is slabbed [65][B][H]
//    and no slab address is ever read before written within this kernel, so
//    L1/L2 can't hold a stale copy. No acquire fence (no buffer_inv).
//    Intra-XCD 32x reuse of the 512KB slab stays L2-served.
//  - flag store: relaxed agent atomic, ordered behind the h stores by an
//    explicit vmcnt(0) drain + __syncthreads.
//  - LDS layout Wl[half][12][514]: bank quad = 16*half + 4*j -> the 8 distinct
//    (j,half) addresses of each ds_read_b128 cover all 32 banks exactly once
//    (conflict-free; old layout was 2-way).
//  - gx loads hoisted before the flag spin (independent of h; latency hides
//    under the spin). h_prev kept in register (thread owns its (b,col) cell).
// Flags carry GLOBAL step count (monotone across chunks). Bounded spin with
// WG-uniform abort (fail-soft).
// ---------------------------------------------------------------------------
__global__ __launch_bounds__(256, 1) void gru_rec(
    const float* __restrict__ W_hh, const float* __restrict__ b_hh,
    const double* __restrict__ gx, double* __restrict__ hs,
    int* __restrict__ flags, int t_base)
{
  __shared__ double Wl[2*12*514];            // [half][rr][514]; rr: 0-3=r,4-7=z,8-11=n
  __shared__ int abort_flag;
  const int tid = threadIdx.x, wg = blockIdx.x;
  const int i0 = wg*4;
  if (tid == 0) abort_flag = 0;

  for (int it = tid; it < 12*1024; it += 256){
    int rr = it >> 10, k = it & 1023;
    int p = rr >> 2, j = rr & 3;
    int hf = k >> 9, kl = k & 511;
    Wl[(hf*12 + rr)*514 + kl] = (double)W_hh[(size_t)(p*H_ + i0 + j)*H_ + k];
  }

  const int bq = tid >> 3, j = (tid >> 1) & 3, half = tid & 1;
  const int b_out = bq*2 + half;
  const int jj = i0 + j;
  const double bh0 = (double)b_hh[jj];
  const double bh1 = (double)b_hh[H_   + jj];
  const double bh2 = (double)b_hh[2*H_ + jj];
  const double2* w0p = (const double2*)&Wl[(half*12 + 0*4 + j)*514];
  const double2* w1p = (const double2*)&Wl[(half*12 + 1*4 + j)*514];
  const double2* w2p = (const double2*)&Wl[(half*12 + 2*4 + j)*514];
  __syncthreads();

  // h_prev for this thread's own (b_out, jj) cell; slot 0 seeded by
  // init_ws (chunk 0) or previous gru_rec launch (kernel-boundary coherent).
  double hprev = hs[(size_t)b_out*H_ + jj];

  for (int tt = 0; tt < TC_; ++tt){
    const int t = t_base + tt;

    // gx is pre-kernel data (stage_a): load BEFORE the spin, hide under it.
    const double* gp = gx + ((size_t)tt*B_ + b_out)*G3_ + jj;
    double gxr = gp[0];
    double gxz = gp[H_];
    double gxn = gp[2*H_];

    {
      int* fp = flags + tid*16;
      int gcnt = 0;
      while (__hip_atomic_load(fp, __ATOMIC_RELAXED, __HIP_MEMORY_SCOPE_AGENT) < t){
        __builtin_amdgcn_s_sleep(2);
        if (++gcnt > (1<<18)) { abort_flag = 1; break; }   // fail-soft
      }
    }
    __syncthreads();                         // also blocks hoist of h loads
    if (abort_flag) break;                   // WG-uniform: all threads bail

    const double2* h0 = (const double2*)(hs + ((size_t)tt*B_ + bq*2    )*H_ + half*512);
    const double2* h1 = (const double2*)(hs + ((size_t)tt*B_ + bq*2 + 1)*H_ + half*512);

    double pr00=0.0, pr10=0.0, pr20=0.0, pr01=0.0, pr11=0.0, pr21=0.0;
    #pragma unroll 8
    for (int kk = 0; kk < 256; ++kk){
      double2 a0 = h0[kk];
      double2 a1 = h1[kk];
      double2 w0 = w0p[kk];
      double2 w1 = w1p[kk];
      double2 w2 = w2p[kk];
      pr00 = fma(a0.x, w0.x, pr00); pr00 = fma(a0.y, w0.y, pr00);
      pr10 = fma(a0.x, w1.x, pr10); pr10 = fma(a0.y, w1.y, pr10);
      pr20 = fma(a0.x, w2.x, pr20); pr20 = fma(a0.y, w2.y, pr20);
      pr01 = fma(a1.x, w0.x, pr01); pr01 = fma(a1.y, w0.y, pr01);
      pr11 = fma(a1.x, w1.x, pr11); pr11 = fma(a1.y, w1.y, pr11);
      pr21 = fma(a1.x, w2.x, pr21); pr21 = fma(a1.y, w2.y, pr21);
    }
    double s00 = pr00 + __shfl_xor(pr00, 1);
    double s01 = pr01 + __shfl_xor(pr01, 1);
    double s10 = pr10 + __shfl_xor(pr10, 1);
    double s11 = pr11 + __shfl_xor(pr11, 1);
    double s20 = pr20 + __shfl_xor(pr20, 1);
    double s21 = pr21 + __shfl_xor(pr21, 1);
    double ar = half ? s01 : s00;
    double az = half ? s11 : s10;
    double an = half ? s21 : s20;

    double rr_ = 1.0/(1.0 + exp(-(gxr + ar + bh0)));
    double zz  = 1.0/(1.0 + exp(-(gxz + az + bh1)));
    double nn  = tanh(gxn + rr_*(an + bh2));
    double hnew = (1.0 - zz)*nn + zz*hprev;
    hprev = hnew;

    // LLC-direct (sc0 sc1) stores: agent-visible without any release fence.
    __hip_atomic_store(&hs[((size_t)(tt+1)*B_ + b_out)*H_ + jj], hnew,
                       __ATOMIC_RELAXED, __HIP_MEMORY_SCOPE_AGENT);
    if (tt == TC_-1)
      __hip_atomic_store(&hs[(size_t)b_out*H_ + jj], hnew,
                         __ATOMIC_RELAXED, __HIP_MEMORY_SCOPE_AGENT);

    asm volatile("s_waitcnt vmcnt(0)" ::: "memory");  // stores acked at LLC
    __syncthreads();                                  // all 4 waves drained
    if (tid == 0)
      __hip_atomic_store(flags + wg*16, t+1, __ATOMIC_RELAXED, __HIP_MEMORY_SCOPE_AGENT);
  }
}

// ---------------------------------------------------------------------------
// FC + sigmoid + labels (per chunk). fp64 accumulation.
// Labels emulate an fp32 sigmoid+threshold: pf = 1/(1+exp32(-logit32)),
// label = pf > 0.5f. (exp32 emulated as correctly-rounded via fp64 exp.)
// Block = batch b: 64 timesteps x 64 outputs, K=1024. grid 64.
// ---------------------------------------------------------------------------
__global__ __launch_bounds__(256) void fc_out(
    const double* __restrict__ hs, const float* __restrict__ W_fc,
    const float* __restrict__ b_fc, float* __restrict__ out, int t_base)
{
  __shared__ double Ah[64][34];
  __shared__ double Bw[64][34];
  const int tid = threadIdx.x;
  const int b = blockIdx.x;
  const int r = tid >> 2, c8 = tid & 3;
  const double* ap = hs   + ((size_t)(r+1)*B_ + b)*H_ + c8*8;   // slot = tl+1
  const float*  bp = W_fc + (size_t)r*H_ + c8*8;
  const int tx = tid & 15, ty = tid >> 4;

  double acc[4][4];
  #pragma unroll
  for (int i = 0; i < 4; ++i)
    #pragma unroll
    for (int j = 0; j < 4; ++j) acc[i][j] = 0.0;

  double ar0[8]; float br0[8];
  #pragma unroll
  for (int e = 0; e < 8; ++e){ ar0[e] = ap[e]; br0[e] = bp[e]; }

  for (int kb = 0; kb < 32; ++kb){
    __syncthreads();
    #pragma unroll
    for (int e = 0; e < 8; ++e){
      Ah[r][c8*8+e] = ar0[e];
      Bw[r][c8*8+e] = (double)br0[e];
    }
    __syncthreads();
    if (kb < 31){
      #pragma unroll
      for (int e = 0; e < 8; ++e){
        ar0[e] = ap[(kb+1)*32 + e];
        br0[e] = bp[(kb+1)*32 + e];
      }
    }
    #pragma unroll
    for (int k = 0; k < 32; ++k){
      double av[4], bv[4];
      #pragma unroll
      for (int i = 0; i < 4; ++i) av[i] = Ah[ty*4+i][k];
      #pragma unroll
      for (int j = 0; j < 4; ++j) bv[j] = Bw[tx*4+j][k];
      #pragma unroll
      for (int i = 0; i < 4; ++i)
        #pragma unroll
        for (int j = 0; j < 4; ++j) acc[i][j] = fma(av[i], bv[j], acc[i][j]);
    }
  }

  double bi[4];
  #pragma unroll
  for (int j = 0; j < 4; ++j) bi[j] = (double)b_fc[tx*4 + j];
  #pragma unroll
  for (int i = 0; i < 4; ++i){
    int tl = ty*4 + i;
    size_t tok = (size_t)b*T_ + t_base + tl;
    float4 pr, lb;
    float* prp = (float*)&pr; float* lbp = (float*)&lb;
    #pragma unroll
    for (int j = 0; j < 4; ++j){
      double logit = acc[i][j] + bi[j];
      prp[j] = (float)(1.0/(1.0 + exp(-logit)));
      // fp32-sigmoid-emulated label rule:
      float lf = (float)logit;                    // fp32 logit
      float ef = (float)exp(-(double)lf);         // correctly-rounded fp32 exp
      float pf = 1.0f / (1.0f + ef);              // fp32 ops thereafter
      lbp[j] = (pf > 0.5f) ? 1.0f : 0.0f;
    }
    *(float4*)&out[tok*O_ + tx*4] = pr;
    *(float4*)&out[(size_t)NTOK*O_ + tok*O_ + tx*4] = lb;
  }
}

// ---------------------------------------------------------------------------
extern "C" void kernel_launch(void* const* d_in, const int* in_sizes, int n_in,
                              void* d_out, int out_size, void* d_ws, size_t ws_size,
                              hipStream_t stream) {
  const int*   x    = (const int*)  d_in[0];
  const float* emb  = (const float*)d_in[1];
  const float* W_ih = (const float*)d_in[2];
  const float* W_hh = (const float*)d_in[3];
  const float* b_ih = (const float*)d_in[4];
  const float* b_hh = (const float*)d_in[5];
  const float* W_fc = (const float*)d_in[6];
  const float* b_fc = (const float*)d_in[7];
  float* out = (float*)d_out;
  char* ws = (char*)d_ws;

  // ws layout (bytes) — total 134,758,400
  double* gx    = (double*)(ws);                 // 64*64*3072*8  = 100,663,296
  double* hs    = (double*)(ws + 100663296);     // 65*64*1024*8  =  34,078,720
  int*    flags = (int*)   (ws + 134742016);     // 16,384

  hipLaunchKernelGGL(init_ws, dim3(256), dim3(256), 0, stream, hs, flags);
  for (int c = 0; c < NCH_; ++c){
    int t_base = c*TC_;
    hipLaunchKernelGGL(stage_a, dim3(3072), dim3(256), 0, stream,
                       x, emb, W_ih, b_ih, gx, t_base);
    hipLaunchKernelGGL(gru_rec, dim3(256), dim3(256), 0, stream,
                       W_hh, b_hh, gx, hs, flags, t_base);
    hipLaunchKernelGGL(fc_out, dim3(64), dim3(256), 0, stream,
                       hs, W_fc, b_fc, out, t_base);
  }
}